// Round 7
// baseline (121.233 us; speedup 1.0000x reference)
//
#include <hip/hip_runtime.h>

// Closed-form: all 10 segment steps are exp(-i*phi_s*H) with the SAME
// traceless Hermitian 2x2 H, so the product is exp(-i*(sum phi)*H).
// infidelity_b = 1 - (cr * sin(DT*S_b*r) / r)^2,  S_b = sum_s omega[b,s]
// loss = mean((infid_data - infidelity)^2)
//
// R6 -> R7: the grid-stride loop guarded EVERY iteration with
// if (t < NTILES), so the compiler kept each iteration's 5 loads behind
// an exec-mask branch -- no cross-iteration load batching. Iterations
// 0..2 are provably in-bounds (tid0 + 2*262144 <= 786431 < 1e6), so
// peel them unconditional and issue all 15 float4 + 3 float2 loads as
// one batch (~66 data VGPRs, 4 waves/SIMD), then one guarded tail.

#define ND 2000000
#define BLK 256
#define NBLOCKS 1024
#define NTHREADS (NBLOCKS * BLK)            // 262,144
#define NTILES (ND / 2)                     // 1,000,000 (2 rows per tile)

__device__ __forceinline__ float tile_term(
    const float4 v0, const float4 v1, const float4 v2,
    const float4 v3, const float4 v4, const float2 fi,
    const float cr_over_r, const float dt_r) {
    const float s0 = ((v0.x + v0.y) + (v0.z + v0.w))
                   + ((v1.x + v1.y) + (v1.z + v1.w)) + (v2.x + v2.y);
    const float s1 = ((v2.z + v2.w) + (v3.x + v3.y))
                   + ((v3.z + v3.w) + (v4.x + v4.y)) + (v4.z + v4.w);
    const float t0 = cr_over_r * sinf(dt_r * s0);
    const float t1 = cr_over_r * sinf(dt_r * s1);
    const float d0 = fi.x - (1.0f - t0 * t0);
    const float d1 = fi.y - (1.0f - t1 * t1);
    return d0 * d0 + d1 * d1;
}

__global__ __launch_bounds__(256) void loss_kernel(
    const float* __restrict__ para,
    const float* __restrict__ omega,
    const float* __restrict__ infid,
    float* __restrict__ partial) {

    // Scalar precompute (broadcast loads, cached)
    const float x00 = para[0], x01 = para[1], x10 = para[2], x11 = para[3];
    const float a  = 0.5f * (x00 - x11);
    const float cr = 0.5f + 0.5f * (x01 + x10);
    const float ci = 0.5f * (x01 - x10);
    const float r  = sqrtf(a * a + cr * cr + ci * ci);
    const float cr_over_r = cr / r;
    const float dt_r = 0.1f * r;            // DT * r

    const unsigned tid0 = (unsigned)blockIdx.x * BLK + threadIdx.x;
    const float4* om4 = (const float4*)omega;
    const float2* fi2 = (const float2*)infid;

    // ---- Iterations 0..2: provably in-bounds, all loads batched ----
    float4 A[3][5];
    float2 F[3];
    #pragma unroll
    for (int it = 0; it < 3; ++it) {
        const unsigned t = tid0 + (unsigned)it * NTHREADS;
        const float4* p4 = om4 + t * 5u;    // t*80 B, 16B-aligned
        #pragma unroll
        for (int k = 0; k < 5; ++k) A[it][k] = p4[k];
        F[it] = fi2[t];
    }

    float acc = 0.0f;
    #pragma unroll
    for (int it = 0; it < 3; ++it)
        acc += tile_term(A[it][0], A[it][1], A[it][2], A[it][3], A[it][4],
                         F[it], cr_over_r, dt_r);

    // ---- Guarded tail iteration ----
    const unsigned t3 = tid0 + 3u * NTHREADS;
    if (t3 < (unsigned)NTILES) {
        const float4* p4 = om4 + t3 * 5u;
        acc += tile_term(p4[0], p4[1], p4[2], p4[3], p4[4],
                         fi2[t3], cr_over_r, dt_r);
    }

    // ---- wave (64-lane) shuffle reduction ----
    #pragma unroll
    for (int off = 32; off > 0; off >>= 1)
        acc += __shfl_down(acc, off, 64);

    __shared__ float wsum[4];               // 256 threads = 4 waves
    const int lane = threadIdx.x & 63;
    const int w    = threadIdx.x >> 6;
    if (lane == 0) wsum[w] = acc;
    __syncthreads();
    if (threadIdx.x == 0) {
        // distinct slot per block: no same-address atomic contention
        partial[blockIdx.x] = (wsum[0] + wsum[1]) + (wsum[2] + wsum[3]);
    }
}

__global__ __launch_bounds__(256) void reduce_kernel(
    const float* __restrict__ partial,
    float* __restrict__ out) {

    const int tid = threadIdx.x;
    float acc = 0.0f;
    #pragma unroll
    for (int i = 0; i < NBLOCKS / 256; ++i)
        acc += partial[tid + 256 * i];

    #pragma unroll
    for (int off = 32; off > 0; off >>= 1)
        acc += __shfl_down(acc, off, 64);

    __shared__ float wsum[4];
    const int lane = tid & 63;
    const int w    = tid >> 6;
    if (lane == 0) wsum[w] = acc;
    __syncthreads();
    if (tid == 0)
        out[0] = ((wsum[0] + wsum[1]) + (wsum[2] + wsum[3])) * (1.0f / (float)ND);
}

extern "C" void kernel_launch(void* const* d_in, const int* in_sizes, int n_in,
                              void* d_out, int out_size, void* d_ws, size_t ws_size,
                              hipStream_t stream) {
    const float* para  = (const float*)d_in[0];   // (2,2)
    const float* omega = (const float*)d_in[1];   // (2M, 10)
    const float* infid = (const float*)d_in[2];   // (2M,)
    float* out     = (float*)d_out;
    float* partial = (float*)d_ws;                // 1024 * 4 B

    loss_kernel<<<NBLOCKS, BLK, 0, stream>>>(para, omega, infid, partial);
    reduce_kernel<<<1, 256, 0, stream>>>(partial, out);
}